// Round 19
// baseline (228.004 us; speedup 1.0000x reference)
//
#include <hip/hip_runtime.h>
#include <hip/hip_bf16.h>
#include <stdint.h>

// ---------------------------------------------------------------------------
// TernaryExpert via INT8 MFMA (R19): delivery-cap model (16 B/cy/CU staged,
// confirmed by R8/R16/R18) says maximize FLOP per staged byte AT >=2 blocks.
// L1 GEMM: 256x256 tile (2x FLOP per 32KB staged vs R18's 256x128/24KB),
// DOUBLE-buffered 64KB LDS -> 2 blocks/CU, drain-0 + 1 barrier per K-tile
// (R17-proven). Predicted L1: 512MB staged /256CU /16B/cy ~ 55us + ovh.
// L2 GEMM (N=1024 -> only 256 blocks at 256-wide): keep R18's 256x128
// triple-buffer counted kernel. Numerics identical (absmax exactly 5.0).
// ---------------------------------------------------------------------------

#define M_ROWS   16384
#define D_MODEL  1024
#define D_FF     4096
#define NW       (D_FF * D_MODEL)

typedef __attribute__((ext_vector_type(4))) int   i32x4;
typedef __attribute__((ext_vector_type(4))) float f32x4;

__device__ __forceinline__ void gload_lds16(const void* g, void* l) {
    __builtin_amdgcn_global_load_lds(
        (const __attribute__((address_space(1))) void*)g,
        (__attribute__((address_space(3))) void*)l, 16, 0, 0);
}

#define BAR()     __builtin_amdgcn_s_barrier()
#define VMCNT(n)  asm volatile("s_waitcnt vmcnt(" #n ")" ::: "memory")

__device__ __forceinline__ float gelu_fast(float v) {
    float w = v * v;
    float z = v * __builtin_fmaf(w, 0.07135481627f, 1.5957691216f);
    float e = __expf(-z);
    return v / (1.0f + e);
}
__device__ __forceinline__ int q8(float v) {
    int q = __float2int_rn(v);
    return (q > 127) ? 127 : ((q < -127) ? -127 : q);
}

// ---------------------------------------------------------------------------
// aux kernels (identical numerics to R13..R18)
// ---------------------------------------------------------------------------
__global__ __launch_bounds__(256) void absmean_reduce(const float* __restrict__ w,
                                                      double* __restrict__ asum) {
    const int n4 = NW / 4;
    float s = 0.f;
    const float4* w4 = (const float4*)w;
    for (int i = blockIdx.x * blockDim.x + threadIdx.x; i < n4;
         i += gridDim.x * blockDim.x) {
        float4 v = w4[i];
        s += fabsf(v.x) + fabsf(v.y) + fabsf(v.z) + fabsf(v.w);
    }
    #pragma unroll
    for (int off = 32; off > 0; off >>= 1) s += __shfl_down(s, off);
    __shared__ float sm[4];
    int lane = threadIdx.x & 63, wid = threadIdx.x >> 6;
    if (lane == 0) sm[wid] = s;
    __syncthreads();
    if (threadIdx.x == 0) {
        float t = sm[0] + sm[1] + sm[2] + sm[3];
        atomicAdd(asum, (double)t);
    }
}

__global__ __launch_bounds__(256) void quant_w8(const float* __restrict__ w,
                                                const double* __restrict__ asum,
                                                char* __restrict__ wq) {
    float thr = (float)(0.5 * (*asum) * (1.0 / (double)NW));
    int i = blockIdx.x * blockDim.x + threadIdx.x;
    float4 v = ((const float4*)w)[i];
    int b0 = (fabsf(v.x) > thr) ? (v.x > 0.f ? 1 : -1) : 0;
    int b1 = (fabsf(v.y) > thr) ? (v.y > 0.f ? 1 : -1) : 0;
    int b2 = (fabsf(v.z) > thr) ? (v.z > 0.f ? 1 : -1) : 0;
    int b3 = (fabsf(v.w) > thr) ? (v.w > 0.f ? 1 : -1) : 0;
    ((int*)wq)[i] = (b0 & 0xff) | ((b1 & 0xff) << 8) |
                    ((b2 & 0xff) << 16) | ((b3 & 0xff) << 24);
}

__global__ __launch_bounds__(256) void rmsnorm_xq(const float* __restrict__ x,
                                                  char* __restrict__ xq) {
    const int row = blockIdx.x;
    const float4* xr = (const float4*)(x + (size_t)row * D_MODEL);
    float4 v = xr[threadIdx.x];
    float ss = v.x * v.x + v.y * v.y + v.z * v.z + v.w * v.w;
    #pragma unroll
    for (int off = 32; off > 0; off >>= 1) ss += __shfl_down(ss, off);
    __shared__ float sm[4];
    int lane = threadIdx.x & 63, wid = threadIdx.x >> 6;
    if (lane == 0) sm[wid] = ss;
    __syncthreads();
    float tot = sm[0] + sm[1] + sm[2] + sm[3];
    float s = 24.0f / (sqrtf(tot) * (1.0f / 32.0f) + 1e-8f);
    int b0 = q8(v.x * s), b1 = q8(v.y * s), b2 = q8(v.z * s), b3 = q8(v.w * s);
    ((int*)(xq + (size_t)row * D_MODEL))[threadIdx.x] =
        (b0 & 0xff) | ((b1 & 0xff) << 8) | ((b2 & 0xff) << 16) | ((b3 & 0xff) << 24);
}

__global__ __launch_bounds__(256) void rowscale_hq(const char* __restrict__ hq,
                                                   float* __restrict__ rs) {
    const int row = blockIdx.x;
    const int4* hr = (const int4*)(hq + (size_t)row * D_FF);
    int4 d = hr[threadIdx.x];
    float ss = 0.f;
    #pragma unroll
    for (int w = 0; w < 4; ++w) {
        int dw = (w == 0) ? d.x : (w == 1) ? d.y : (w == 2) ? d.z : d.w;
        #pragma unroll
        for (int b = 0; b < 4; ++b) {
            int q = (int)(char)((dw >> (8 * b)) & 0xff);
            ss += (float)(q * q);
        }
    }
    #pragma unroll
    for (int off = 32; off > 0; off >>= 1) ss += __shfl_down(ss, off);
    __shared__ float sm[4];
    int lane = threadIdx.x & 63, wid = threadIdx.x >> 6;
    if (lane == 0) sm[wid] = ss;
    __syncthreads();
    if (threadIdx.x == 0) {
        float tot = sm[0] + sm[1] + sm[2] + sm[3];
        rs[row] = 1.0f / (sqrtf(tot) * (1.0f / 64.0f) + 1e-8f);
    }
}

// ---------------------------------------------------------------------------
// L1 GEMM: 256x256, BK=64. LDS buffer (32KB): A 256x64B @0, B 256x64B @16384.
// 2 buffers (64KB) -> 2 blocks/CU. 8 waves (2Mx4N, 128x64/wave).
// Per tile: 12 ds_read + 4 gload_lds + 32 MFMA + vmcnt(0) + 1 barrier.
// ---------------------------------------------------------------------------
template <int KDIM, int NBLKN>
__global__ __launch_bounds__(512) void gemm_i8big(const char* __restrict__ A,
                                                  const char* __restrict__ B,
                                                  char* __restrict__ Cq,
                                                  int nwg) {
    constexpr int BUFB = 32768;
    constexpr int NT = KDIM / 64;
    __shared__ char smem[2 * BUFB];

    const int tid = threadIdx.x;
    const int bid = blockIdx.x;
    const int swz = (bid & 7) * (nwg >> 3) + (bid >> 3);
    const uint m0 = (uint)(swz / NBLKN) * 256u;
    const uint n0 = (uint)(swz % NBLKN) * 256u;

    const int lane = tid & 63;
    const int wid  = tid >> 6;
    const int wm   = wid >> 2;                  // 0..1 -> 128-row slice
    const int wn   = wid & 3;                   // 0..3 -> 64-col slice
    const int lr   = lane & 15;
    const int lk   = lane >> 4;                 // 16B k-chunk 0..3

    // staging source (inverse swizzle), per inst in {0,1}
    uint aOff[2], bOff[2];
    #pragma unroll
    for (int inst = 0; inst < 2; ++inst) {
        uint s = (uint)tid + (uint)inst * 512u;
        uint row = s >> 2, ch = s & 3u;
        uint src = ((ch ^ ((row >> 1) & 3u)) << 4);
        aOff[inst] = (m0 + row) * (uint)KDIM + src;
        bOff[inst] = (n0 + row) * (uint)KDIM + src;
    }
    const uint dstOff = (uint)tid * 16u;

    // fragment read offsets (bytes)
    uint offA[8], offB[4];
    #pragma unroll
    for (int i = 0; i < 8; ++i) {
        uint row = (uint)(wm * 128 + i * 16 + lr);
        offA[i] = row * 64u + (((uint)lk ^ ((row >> 1) & 3u)) << 4);
    }
    #pragma unroll
    for (int i = 0; i < 4; ++i) {
        uint row = (uint)(wn * 64 + i * 16 + lr);
        offB[i] = 16384u + row * 64u + (((uint)lk ^ ((row >> 1) & 3u)) << 4);
    }

    i32x4 acc[8][4];
    #pragma unroll
    for (int mi = 0; mi < 8; ++mi)
        #pragma unroll
        for (int ni = 0; ni < 4; ++ni)
            acc[mi][ni] = (i32x4){0, 0, 0, 0};

    // prologue: stage tile 0 into buf 0
    {
        gload_lds16(A + aOff[0], smem +     0 + dstOff);
        gload_lds16(A + aOff[1], smem +  8192 + dstOff);
        gload_lds16(B + bOff[0], smem + 16384 + dstOff);
        gload_lds16(B + bOff[1], smem + 24576 + dstOff);
    }
    VMCNT(0);
    BAR();

    #pragma unroll 1
    for (int t = 0; t < NT; ++t) {
        const char* cb = smem + (t & 1) * BUFB;
        char* sb = smem + ((t + 1) & 1) * BUFB;
        const uint kc = (uint)(t + 1) * 64u;
        const bool doS = (t + 1 < NT);
        i32x4 av[4], bv[4];

        // P1: A-h0 + all B reads; stage A(t+1); 16 MFMA
        #pragma unroll
        for (int i = 0; i < 4; ++i) av[i] = *(const i32x4*)(cb + offA[i]);
        #pragma unroll
        for (int i = 0; i < 4; ++i) bv[i] = *(const i32x4*)(cb + offB[i]);
        if (doS) {
            gload_lds16(A + aOff[0] + kc, sb +    0 + dstOff);
            gload_lds16(A + aOff[1] + kc, sb + 8192 + dstOff);
        }
        __builtin_amdgcn_s_setprio(1);
        #pragma unroll
        for (int mi = 0; mi < 4; ++mi)
            #pragma unroll
            for (int ni = 0; ni < 4; ++ni)
                acc[mi][ni] = __builtin_amdgcn_mfma_i32_16x16x64_i8(
                    av[mi], bv[ni], acc[mi][ni], 0, 0, 0);
        __builtin_amdgcn_s_setprio(0);

        // P2: A-h1 reads (B reg-reused); stage B(t+1); 16 MFMA
        #pragma unroll
        for (int i = 0; i < 4; ++i) av[i] = *(const i32x4*)(cb + offA[4 + i]);
        if (doS) {
            gload_lds16(B + bOff[0] + kc, sb + 16384 + dstOff);
            gload_lds16(B + bOff[1] + kc, sb + 24576 + dstOff);
        }
        __builtin_amdgcn_s_setprio(1);
        #pragma unroll
        for (int mi = 0; mi < 4; ++mi)
            #pragma unroll
            for (int ni = 0; ni < 4; ++ni)
                acc[4 + mi][ni] = __builtin_amdgcn_mfma_i32_16x16x64_i8(
                    av[mi], bv[ni], acc[4 + mi][ni], 0, 0, 0);
        __builtin_amdgcn_s_setprio(0);

        if (doS) { VMCNT(0); }
        BAR();
    }

    // epilogue: gelu -> q8
    constexpr uint N = (uint)NBLKN * 256u;
    #pragma unroll
    for (int mi = 0; mi < 8; ++mi) {
        #pragma unroll
        for (int j = 0; j < 4; ++j) {
            const uint gr = m0 + (uint)(wm * 128 + mi * 16 + lk * 4 + j);
            #pragma unroll
            for (int ni = 0; ni < 4; ++ni) {
                const uint gc = n0 + (uint)(wn * 64 + ni * 16 + lr);
                float g = gelu_fast((float)acc[mi][ni][j] * (1.0f / 24.0f));
                Cq[gr * N + gc] = (char)q8(g);
            }
        }
    }
}

// ---------------------------------------------------------------------------
// L2 GEMM: R18's 256x128 triple-buffer counted kernel (unchanged).
// ---------------------------------------------------------------------------
template <int KDIM, int NBLKN>
__global__ __launch_bounds__(512) void gemm_i8t(const char* __restrict__ A,
                                                const char* __restrict__ B,
                                                float* __restrict__ Cf,
                                                const float* __restrict__ rowscale,
                                                int nwg) {
    constexpr int BUFB = 24576;
    constexpr int NT = KDIM / 64;
    __shared__ char smem[3 * BUFB];

    const int tid = threadIdx.x;
    const int bid = blockIdx.x;
    const int swz = (bid & 7) * (nwg >> 3) + (bid >> 3);
    const uint m0 = (uint)(swz / NBLKN) * 256u;
    const uint n0 = (uint)(swz % NBLKN) * 128u;

    const int lane = tid & 63;
    const int wid  = tid >> 6;
    const int wm   = wid >> 1;
    const int wn   = wid & 1;
    const int lr   = lane & 15;
    const int lk   = lane >> 4;

    uint aOff[2], bOff;
    #pragma unroll
    for (int inst = 0; inst < 2; ++inst) {
        uint s = (uint)tid + (uint)inst * 512u;
        uint row = s >> 2, ch = s & 3u;
        uint src = ((ch ^ ((row >> 1) & 3u)) << 4);
        aOff[inst] = (m0 + row) * (uint)KDIM + src;
    }
    {
        uint row = (uint)tid >> 2, ch = (uint)tid & 3u;
        uint src = ((ch ^ ((row >> 1) & 3u)) << 4);
        bOff = (n0 + row) * (uint)KDIM + src;
    }
    const uint dstOff = (uint)tid * 16u;

    uint offA[4], offB[4];
    #pragma unroll
    for (int i = 0; i < 4; ++i) {
        uint rowa = (uint)(wm * 64 + i * 16 + lr);
        offA[i] = rowa * 64u + (((uint)lk ^ ((rowa >> 1) & 3u)) << 4);
        uint rowb = (uint)(wn * 64 + i * 16 + lr);
        offB[i] = 16384u + rowb * 64u + (((uint)lk ^ ((rowb >> 1) & 3u)) << 4);
    }

    i32x4 acc[4][4];
    #pragma unroll
    for (int mi = 0; mi < 4; ++mi)
        #pragma unroll
        for (int ni = 0; ni < 4; ++ni)
            acc[mi][ni] = (i32x4){0, 0, 0, 0};

    #pragma unroll
    for (int tt = 0; tt < 2; ++tt) {
        char* sb = smem + tt * BUFB;
        const uint k0 = (uint)tt * 64u;
        gload_lds16(A + aOff[0] + k0, sb +     0 + dstOff);
        gload_lds16(A + aOff[1] + k0, sb +  8192 + dstOff);
        gload_lds16(B + bOff    + k0, sb + 16384 + dstOff);
    }
    VMCNT(3);
    BAR();

    int cur = 0, stg = 2;
    #pragma unroll 1
    for (int t = 0; t < NT; ++t) {
        const char* cb = smem + cur * BUFB;
        char* sb = smem + stg * BUFB;
        const uint kc = (uint)(t + 2) * 64u;
        const bool doS = (t + 2 < NT);
        i32x4 av[4], bv[4];

        #pragma unroll
        for (int i = 0; i < 4; ++i) av[i] = *(const i32x4*)(cb + offA[i]);
        #pragma unroll
        for (int i = 0; i < 4; ++i) bv[i] = *(const i32x4*)(cb + offB[i]);
        if (doS) {
            gload_lds16(A + aOff[0] + kc, sb +     0 + dstOff);
            gload_lds16(A + aOff[1] + kc, sb +  8192 + dstOff);
            gload_lds16(B + bOff    + kc, sb + 16384 + dstOff);
        }
        __builtin_amdgcn_s_setprio(1);
        #pragma unroll
        for (int mi = 0; mi < 4; ++mi)
            #pragma unroll
            for (int ni = 0; ni < 4; ++ni)
                acc[mi][ni] = __builtin_amdgcn_mfma_i32_16x16x64_i8(
                    av[mi], bv[ni], acc[mi][ni], 0, 0, 0);
        __builtin_amdgcn_s_setprio(0);

        if (doS) { VMCNT(3); } else { VMCNT(0); }
        BAR();
        cur = (cur == 2) ? 0 : cur + 1;
        stg = (stg == 2) ? 0 : stg + 1;
    }

    constexpr uint N = (uint)NBLKN * 128u;
    #pragma unroll
    for (int mi = 0; mi < 4; ++mi) {
        #pragma unroll
        for (int j = 0; j < 4; ++j) {
            const uint gr = m0 + (uint)(wm * 64 + mi * 16 + lk * 4 + j);
            float s = rowscale[gr];
            #pragma unroll
            for (int ni = 0; ni < 4; ++ni) {
                const uint gc = n0 + (uint)(wn * 64 + ni * 16 + lr);
                Cf[gr * N + gc] = (float)acc[mi][ni][j] * s;
            }
        }
    }
}

// ---------------------------------------------------------------------------
extern "C" void kernel_launch(void* const* d_in, const int* in_sizes, int n_in,
                              void* d_out, int out_size, void* d_ws, size_t ws_size,
                              hipStream_t stream) {
    const float* x    = (const float*)d_in[0];
    const float* w_up = (const float*)d_in[1];
    const float* w_dn = (const float*)d_in[2];
    float* out = (float*)d_out;

    uint8_t* ws = (uint8_t*)d_ws;
    char* hq  = (char*)(ws);                                   // 64 MB
    char* xq  = (char*)(ws + 67108864);                        // 16 MB
    char* wqu = (char*)(ws + 67108864 + 16777216);             // 4 MB
    char* wqd = (char*)(ws + 67108864 + 16777216 + 4194304);   // 4 MB
    float*  rs   = (float*)(ws + 67108864 + 16777216 + 2 * 4194304);
    double* alph = (double*)(ws + 67108864 + 16777216 + 2 * 4194304 + 65536);

    hipMemsetAsync(alph, 0, 16, stream);

    absmean_reduce<<<256, 256, 0, stream>>>(w_up, alph + 0);
    absmean_reduce<<<256, 256, 0, stream>>>(w_dn, alph + 1);
    quant_w8<<<NW / 1024, 256, 0, stream>>>(w_up, alph + 0, wqu);
    quant_w8<<<NW / 1024, 256, 0, stream>>>(w_dn, alph + 1, wqd);
    rmsnorm_xq<<<M_ROWS, 256, 0, stream>>>(x, xq);

    // L1: hq = q8(gelu((xq @ wqu^T)/24))  [16384 x 4096], K=1024
    // 256x256 tile -> grid 64 x 16 = 1024 blocks, 2 blocks/CU
    gemm_i8big<D_MODEL, 16><<<1024, 512, 0, stream>>>(xq, wqu, hq, 1024);

    rowscale_hq<<<M_ROWS, 256, 0, stream>>>(hq, rs);

    // L2: out = (hq @ wqd^T) * rs[m]  [16384 x 1024], K=4096
    // 256x128 tile -> grid 64 x 8 = 512 blocks
    gemm_i8t<D_FF, 8><<<512, 512, 0, stream>>>(hq, wqd, out, rs, 512);
}

// Round 20
// 223.593 us; speedup vs baseline: 1.0197x; 1.0197x over previous
//
#include <hip/hip_runtime.h>
#include <hip/hip_bf16.h>
#include <stdint.h>

// ---------------------------------------------------------------------------
// TernaryExpert via INT8 MFMA (R20: full-line staging x multi-block):
// All prior i8 configs staged 64-B rows (BK=64) -> each read uses half a
// 128-B L2 line; all ~16 B/cy/CU observations were half-line+multiblock.
// R20 tests the untested cell: BK=128 (128-B rows, full-line) + 2 blocks/CU.
// 128x128 tile, 256 thr (4 waves 2x2, 64x64/wave, acc=64 AGPR -> ~105 regs,
// fits 16 waves/CU), double-buffered 2x32KB LDS -> 2 blocks/CU.
// Staging: 8 consecutive threads = one full 128-B row; swizzle ch ^= row&7
// (uniform banks), inverse-applied at the global source (rule #21).
// Per K-tile: 16 ds_read + 8 gload_lds + 32 MFMA + vmcnt(0) + 1 barrier.
// Numerics identical to R13..R19 (absmax exactly 5.0).
// ---------------------------------------------------------------------------

#define M_ROWS   16384
#define D_MODEL  1024
#define D_FF     4096
#define NW       (D_FF * D_MODEL)

typedef __attribute__((ext_vector_type(4))) int   i32x4;
typedef __attribute__((ext_vector_type(4))) float f32x4;

__device__ __forceinline__ void gload_lds16(const void* g, void* l) {
    __builtin_amdgcn_global_load_lds(
        (const __attribute__((address_space(1))) void*)g,
        (__attribute__((address_space(3))) void*)l, 16, 0, 0);
}

#define BAR()     __builtin_amdgcn_s_barrier()
#define VMCNT(n)  asm volatile("s_waitcnt vmcnt(" #n ")" ::: "memory")

__device__ __forceinline__ float gelu_fast(float v) {
    float w = v * v;
    float z = v * __builtin_fmaf(w, 0.07135481627f, 1.5957691216f);
    float e = __expf(-z);
    return v / (1.0f + e);
}
__device__ __forceinline__ int q8(float v) {
    int q = __float2int_rn(v);
    return (q > 127) ? 127 : ((q < -127) ? -127 : q);
}

// ---------------------------------------------------------------------------
// aux kernels (identical numerics to R13..R19)
// ---------------------------------------------------------------------------
__global__ __launch_bounds__(256) void absmean_reduce(const float* __restrict__ w,
                                                      double* __restrict__ asum) {
    const int n4 = NW / 4;
    float s = 0.f;
    const float4* w4 = (const float4*)w;
    for (int i = blockIdx.x * blockDim.x + threadIdx.x; i < n4;
         i += gridDim.x * blockDim.x) {
        float4 v = w4[i];
        s += fabsf(v.x) + fabsf(v.y) + fabsf(v.z) + fabsf(v.w);
    }
    #pragma unroll
    for (int off = 32; off > 0; off >>= 1) s += __shfl_down(s, off);
    __shared__ float sm[4];
    int lane = threadIdx.x & 63, wid = threadIdx.x >> 6;
    if (lane == 0) sm[wid] = s;
    __syncthreads();
    if (threadIdx.x == 0) {
        float t = sm[0] + sm[1] + sm[2] + sm[3];
        atomicAdd(asum, (double)t);
    }
}

__global__ __launch_bounds__(256) void quant_w8(const float* __restrict__ w,
                                                const double* __restrict__ asum,
                                                char* __restrict__ wq) {
    float thr = (float)(0.5 * (*asum) * (1.0 / (double)NW));
    int i = blockIdx.x * blockDim.x + threadIdx.x;
    float4 v = ((const float4*)w)[i];
    int b0 = (fabsf(v.x) > thr) ? (v.x > 0.f ? 1 : -1) : 0;
    int b1 = (fabsf(v.y) > thr) ? (v.y > 0.f ? 1 : -1) : 0;
    int b2 = (fabsf(v.z) > thr) ? (v.z > 0.f ? 1 : -1) : 0;
    int b3 = (fabsf(v.w) > thr) ? (v.w > 0.f ? 1 : -1) : 0;
    ((int*)wq)[i] = (b0 & 0xff) | ((b1 & 0xff) << 8) |
                    ((b2 & 0xff) << 16) | ((b3 & 0xff) << 24);
}

__global__ __launch_bounds__(256) void rmsnorm_xq(const float* __restrict__ x,
                                                  char* __restrict__ xq) {
    const int row = blockIdx.x;
    const float4* xr = (const float4*)(x + (size_t)row * D_MODEL);
    float4 v = xr[threadIdx.x];
    float ss = v.x * v.x + v.y * v.y + v.z * v.z + v.w * v.w;
    #pragma unroll
    for (int off = 32; off > 0; off >>= 1) ss += __shfl_down(ss, off);
    __shared__ float sm[4];
    int lane = threadIdx.x & 63, wid = threadIdx.x >> 6;
    if (lane == 0) sm[wid] = ss;
    __syncthreads();
    float tot = sm[0] + sm[1] + sm[2] + sm[3];
    float s = 24.0f / (sqrtf(tot) * (1.0f / 32.0f) + 1e-8f);
    int b0 = q8(v.x * s), b1 = q8(v.y * s), b2 = q8(v.z * s), b3 = q8(v.w * s);
    ((int*)(xq + (size_t)row * D_MODEL))[threadIdx.x] =
        (b0 & 0xff) | ((b1 & 0xff) << 8) | ((b2 & 0xff) << 16) | ((b3 & 0xff) << 24);
}

__global__ __launch_bounds__(256) void rowscale_hq(const char* __restrict__ hq,
                                                   float* __restrict__ rs) {
    const int row = blockIdx.x;
    const int4* hr = (const int4*)(hq + (size_t)row * D_FF);
    int4 d = hr[threadIdx.x];
    float ss = 0.f;
    #pragma unroll
    for (int w = 0; w < 4; ++w) {
        int dw = (w == 0) ? d.x : (w == 1) ? d.y : (w == 2) ? d.z : d.w;
        #pragma unroll
        for (int b = 0; b < 4; ++b) {
            int q = (int)(char)((dw >> (8 * b)) & 0xff);
            ss += (float)(q * q);
        }
    }
    #pragma unroll
    for (int off = 32; off > 0; off >>= 1) ss += __shfl_down(ss, off);
    __shared__ float sm[4];
    int lane = threadIdx.x & 63, wid = threadIdx.x >> 6;
    if (lane == 0) sm[wid] = ss;
    __syncthreads();
    if (threadIdx.x == 0) {
        float tot = sm[0] + sm[1] + sm[2] + sm[3];
        rs[row] = 1.0f / (sqrtf(tot) * (1.0f / 64.0f) + 1e-8f);
    }
}

// ---------------------------------------------------------------------------
// i8 GEMM: C[m][n] = sum_k A[m,k]*B[n,k], A/B i8 K-contig.
// 128x128 tile, BK=128 (128-B rows = full L2 lines). LDS buffer (32KB):
// A 128x128B @0, B 128x128B @16384; 2 buffers (64KB) -> 2 blocks/CU.
// Swizzle: 8 chunks/row, ch ^= (row&7); read addr r*128 + ((ks4+lk)^(r&7))*16
// where ks=1 offset = ks=0 offset ^ 64. Staging slot s: row=s>>3, ch=s&7,
// src = row*KDIM + (ch^(row&7))*16 -> 8 consecutive threads = full 128-B row.
// Per K-tile: 16 ds_read + 8 gload_lds + 32 MFMA + vmcnt(0) + 1 barrier.
// ---------------------------------------------------------------------------
template <int EPI, int KDIM, int NBLKN>
__global__ __launch_bounds__(256) void gemm_i8f(const char* __restrict__ A,
                                                const char* __restrict__ B,
                                                char* __restrict__ Cq,
                                                float* __restrict__ Cf,
                                                const float* __restrict__ rowscale,
                                                int nwg) {
    constexpr int BUFB = 32768;
    constexpr int NT = KDIM / 128;
    __shared__ char smem[2 * BUFB];

    const int tid = threadIdx.x;
    const int bid = blockIdx.x;
    const int swz = (bid & 7) * (nwg >> 3) + (bid >> 3);
    const uint m0 = (uint)(swz / NBLKN) * 128u;
    const uint n0 = (uint)(swz % NBLKN) * 128u;

    const int lane = tid & 63;
    const int wid  = tid >> 6;
    const int wm   = wid >> 1;                  // 0..1 -> 64-row slice
    const int wn   = wid & 1;                   // 0..1 -> 64-col slice
    const int lr   = lane & 15;
    const int lk   = lane >> 4;                 // 16B k-chunk within 64B

    // staging source (inverse swizzle), per inst in {0..3}: slots tid+inst*256
    uint aOff[4], bOff[4];
    #pragma unroll
    for (int inst = 0; inst < 4; ++inst) {
        uint s = (uint)tid + (uint)inst * 256u;
        uint row = s >> 3, ch = s & 7u;
        uint src = ((ch ^ (row & 7u)) << 4);
        aOff[inst] = (m0 + row) * (uint)KDIM + src;
        bOff[inst] = (n0 + row) * (uint)KDIM + src;
    }
    const uint dstOff = (uint)tid * 16u;

    // fragment read offsets (bytes), ks=0; ks=1 = ^64
    uint offA[4], offB[4];
    #pragma unroll
    for (int i = 0; i < 4; ++i) {
        uint rowa = (uint)(wm * 64 + i * 16 + lr);
        offA[i] = rowa * 128u + ((((uint)lk) ^ (rowa & 7u)) << 4);
        uint rowb = (uint)(wn * 64 + i * 16 + lr);
        offB[i] = 16384u + rowb * 128u + ((((uint)lk) ^ (rowb & 7u)) << 4);
    }

    i32x4 acc[4][4];
    #pragma unroll
    for (int mi = 0; mi < 4; ++mi)
        #pragma unroll
        for (int ni = 0; ni < 4; ++ni)
            acc[mi][ni] = (i32x4){0, 0, 0, 0};

    // prologue: stage tile 0 into buf 0
    {
        #pragma unroll
        for (int i = 0; i < 4; ++i)
            gload_lds16(A + aOff[i], smem + i * 4096 + dstOff);
        #pragma unroll
        for (int i = 0; i < 4; ++i)
            gload_lds16(B + bOff[i], smem + 16384 + i * 4096 + dstOff);
    }
    VMCNT(0);
    BAR();

    #pragma unroll 1
    for (int t = 0; t < NT; ++t) {
        const char* cb = smem + (t & 1) * BUFB;
        char* sb = smem + ((t + 1) & 1) * BUFB;
        const uint kc = (uint)(t + 1) * 128u;
        const bool doS = (t + 1 < NT);
        i32x4 av0[4], bv0[4], av1[4], bv1[4];

        #pragma unroll
        for (int i = 0; i < 4; ++i) {
            av0[i] = *(const i32x4*)(cb + offA[i]);
            av1[i] = *(const i32x4*)(cb + (offA[i] ^ 64u));
        }
        #pragma unroll
        for (int i = 0; i < 4; ++i) {
            bv0[i] = *(const i32x4*)(cb + offB[i]);
            bv1[i] = *(const i32x4*)(cb + (offB[i] ^ 64u));
        }
        if (doS) {
            #pragma unroll
            for (int i = 0; i < 4; ++i)
                gload_lds16(A + aOff[i] + kc, sb + i * 4096 + dstOff);
            #pragma unroll
            for (int i = 0; i < 4; ++i)
                gload_lds16(B + bOff[i] + kc, sb + 16384 + i * 4096 + dstOff);
        }
        __builtin_amdgcn_s_setprio(1);
        #pragma unroll
        for (int mi = 0; mi < 4; ++mi)
            #pragma unroll
            for (int ni = 0; ni < 4; ++ni)
                acc[mi][ni] = __builtin_amdgcn_mfma_i32_16x16x64_i8(
                    av0[mi], bv0[ni], acc[mi][ni], 0, 0, 0);
        #pragma unroll
        for (int mi = 0; mi < 4; ++mi)
            #pragma unroll
            for (int ni = 0; ni < 4; ++ni)
                acc[mi][ni] = __builtin_amdgcn_mfma_i32_16x16x64_i8(
                    av1[mi], bv1[ni], acc[mi][ni], 0, 0, 0);
        __builtin_amdgcn_s_setprio(0);

        if (doS) { VMCNT(0); }
        BAR();
    }

    // epilogue: C/D frag mapping col = lane&15, row = (lane>>4)*4 + reg
    constexpr uint N = (uint)NBLKN * 128u;
    #pragma unroll
    for (int mi = 0; mi < 4; ++mi) {
        #pragma unroll
        for (int j = 0; j < 4; ++j) {
            const uint gr = m0 + (uint)(wm * 64 + mi * 16 + lk * 4 + j);
            float s = 0.f;
            if (EPI == 1) s = rowscale[gr];
            #pragma unroll
            for (int ni = 0; ni < 4; ++ni) {
                const uint gc = n0 + (uint)(wn * 64 + ni * 16 + lr);
                if (EPI == 0) {
                    float g = gelu_fast((float)acc[mi][ni][j] * (1.0f / 24.0f));
                    Cq[gr * N + gc] = (char)q8(g);
                } else {
                    Cf[gr * N + gc] = (float)acc[mi][ni][j] * s;
                }
            }
        }
    }
}

// ---------------------------------------------------------------------------
extern "C" void kernel_launch(void* const* d_in, const int* in_sizes, int n_in,
                              void* d_out, int out_size, void* d_ws, size_t ws_size,
                              hipStream_t stream) {
    const float* x    = (const float*)d_in[0];
    const float* w_up = (const float*)d_in[1];
    const float* w_dn = (const float*)d_in[2];
    float* out = (float*)d_out;

    uint8_t* ws = (uint8_t*)d_ws;
    char* hq  = (char*)(ws);                                   // 64 MB
    char* xq  = (char*)(ws + 67108864);                        // 16 MB
    char* wqu = (char*)(ws + 67108864 + 16777216);             // 4 MB
    char* wqd = (char*)(ws + 67108864 + 16777216 + 4194304);   // 4 MB
    float*  rs   = (float*)(ws + 67108864 + 16777216 + 2 * 4194304);
    double* alph = (double*)(ws + 67108864 + 16777216 + 2 * 4194304 + 65536);

    hipMemsetAsync(alph, 0, 16, stream);

    absmean_reduce<<<256, 256, 0, stream>>>(w_up, alph + 0);
    absmean_reduce<<<256, 256, 0, stream>>>(w_dn, alph + 1);
    quant_w8<<<NW / 1024, 256, 0, stream>>>(w_up, alph + 0, wqu);
    quant_w8<<<NW / 1024, 256, 0, stream>>>(w_dn, alph + 1, wqd);
    rmsnorm_xq<<<M_ROWS, 256, 0, stream>>>(x, xq);

    // L1: hq = q8(gelu((xq @ wqu^T)/24))  [16384 x 4096], K=1024
    // 128x128 tile -> grid 128 x 32 = 4096 blocks
    gemm_i8f<0, D_MODEL, 32><<<4096, 256, 0, stream>>>(
        xq, wqu, hq, nullptr, nullptr, 4096);

    rowscale_hq<<<M_ROWS, 256, 0, stream>>>(hq, rs);

    // L2: out = (hq @ wqd^T) * rs[m]  [16384 x 1024], K=4096
    // 128x128 tile -> grid 128 x 8 = 1024 blocks
    gemm_i8f<1, D_FF, 8><<<1024, 256, 0, stream>>>(
        hq, wqd, nullptr, out, rs, 1024);
}

// Round 21
// 221.249 us; speedup vs baseline: 1.0305x; 1.0106x over previous
//
#include <hip/hip_runtime.h>
#include <hip/hip_bf16.h>
#include <stdint.h>

// ---------------------------------------------------------------------------
// TernaryExpert via INT8 MFMA (R21 = R18 + XCD-L2-locality grid for L1):
// R18's FETCH showed ~6x HBM over-fetch on L1: old swizzle gave each XCD a
// bid-range spanning ALL m-tiles -> every XCD streamed the whole 16MB A
// through its 4MB L2 (8x16=128MB ~ measured 115-140MB). R21 maps each XCD
// to an 8-m-tile stripe (A slice 2MB, L2-resident), m-major inner order so
// B panels stream: per-XCD fetch ~ 2+4MB -> ~48MB total. L2 GEMM unchanged
// (R18 256x128 triple-buffer counted). Numerics identical (absmax 5.0).
// ---------------------------------------------------------------------------

#define M_ROWS   16384
#define D_MODEL  1024
#define D_FF     4096
#define NW       (D_FF * D_MODEL)

typedef __attribute__((ext_vector_type(4))) int   i32x4;
typedef __attribute__((ext_vector_type(4))) float f32x4;

__device__ __forceinline__ void gload_lds16(const void* g, void* l) {
    __builtin_amdgcn_global_load_lds(
        (const __attribute__((address_space(1))) void*)g,
        (__attribute__((address_space(3))) void*)l, 16, 0, 0);
}

#define BAR()     __builtin_amdgcn_s_barrier()
#define VMCNT(n)  asm volatile("s_waitcnt vmcnt(" #n ")" ::: "memory")

__device__ __forceinline__ float gelu_fast(float v) {
    float w = v * v;
    float z = v * __builtin_fmaf(w, 0.07135481627f, 1.5957691216f);
    float e = __expf(-z);
    return v / (1.0f + e);
}
__device__ __forceinline__ int q8(float v) {
    int q = __float2int_rn(v);
    return (q > 127) ? 127 : ((q < -127) ? -127 : q);
}

// ---------------------------------------------------------------------------
// aux kernels (identical numerics to R13..R20)
// ---------------------------------------------------------------------------
__global__ __launch_bounds__(256) void absmean_reduce(const float* __restrict__ w,
                                                      double* __restrict__ asum) {
    const int n4 = NW / 4;
    float s = 0.f;
    const float4* w4 = (const float4*)w;
    for (int i = blockIdx.x * blockDim.x + threadIdx.x; i < n4;
         i += gridDim.x * blockDim.x) {
        float4 v = w4[i];
        s += fabsf(v.x) + fabsf(v.y) + fabsf(v.z) + fabsf(v.w);
    }
    #pragma unroll
    for (int off = 32; off > 0; off >>= 1) s += __shfl_down(s, off);
    __shared__ float sm[4];
    int lane = threadIdx.x & 63, wid = threadIdx.x >> 6;
    if (lane == 0) sm[wid] = s;
    __syncthreads();
    if (threadIdx.x == 0) {
        float t = sm[0] + sm[1] + sm[2] + sm[3];
        atomicAdd(asum, (double)t);
    }
}

__global__ __launch_bounds__(256) void quant_w8(const float* __restrict__ w,
                                                const double* __restrict__ asum,
                                                char* __restrict__ wq) {
    float thr = (float)(0.5 * (*asum) * (1.0 / (double)NW));
    int i = blockIdx.x * blockDim.x + threadIdx.x;
    float4 v = ((const float4*)w)[i];
    int b0 = (fabsf(v.x) > thr) ? (v.x > 0.f ? 1 : -1) : 0;
    int b1 = (fabsf(v.y) > thr) ? (v.y > 0.f ? 1 : -1) : 0;
    int b2 = (fabsf(v.z) > thr) ? (v.z > 0.f ? 1 : -1) : 0;
    int b3 = (fabsf(v.w) > thr) ? (v.w > 0.f ? 1 : -1) : 0;
    ((int*)wq)[i] = (b0 & 0xff) | ((b1 & 0xff) << 8) |
                    ((b2 & 0xff) << 16) | ((b3 & 0xff) << 24);
}

__global__ __launch_bounds__(256) void rmsnorm_xq(const float* __restrict__ x,
                                                  char* __restrict__ xq) {
    const int row = blockIdx.x;
    const float4* xr = (const float4*)(x + (size_t)row * D_MODEL);
    float4 v = xr[threadIdx.x];
    float ss = v.x * v.x + v.y * v.y + v.z * v.z + v.w * v.w;
    #pragma unroll
    for (int off = 32; off > 0; off >>= 1) ss += __shfl_down(ss, off);
    __shared__ float sm[4];
    int lane = threadIdx.x & 63, wid = threadIdx.x >> 6;
    if (lane == 0) sm[wid] = ss;
    __syncthreads();
    float tot = sm[0] + sm[1] + sm[2] + sm[3];
    float s = 24.0f / (sqrtf(tot) * (1.0f / 32.0f) + 1e-8f);
    int b0 = q8(v.x * s), b1 = q8(v.y * s), b2 = q8(v.z * s), b3 = q8(v.w * s);
    ((int*)(xq + (size_t)row * D_MODEL))[threadIdx.x] =
        (b0 & 0xff) | ((b1 & 0xff) << 8) | ((b2 & 0xff) << 16) | ((b3 & 0xff) << 24);
}

__global__ __launch_bounds__(256) void rowscale_hq(const char* __restrict__ hq,
                                                   float* __restrict__ rs) {
    const int row = blockIdx.x;
    const int4* hr = (const int4*)(hq + (size_t)row * D_FF);
    int4 d = hr[threadIdx.x];
    float ss = 0.f;
    #pragma unroll
    for (int w = 0; w < 4; ++w) {
        int dw = (w == 0) ? d.x : (w == 1) ? d.y : (w == 2) ? d.z : d.w;
        #pragma unroll
        for (int b = 0; b < 4; ++b) {
            int q = (int)(char)((dw >> (8 * b)) & 0xff);
            ss += (float)(q * q);
        }
    }
    #pragma unroll
    for (int off = 32; off > 0; off >>= 1) ss += __shfl_down(ss, off);
    __shared__ float sm[4];
    int lane = threadIdx.x & 63, wid = threadIdx.x >> 6;
    if (lane == 0) sm[wid] = ss;
    __syncthreads();
    if (threadIdx.x == 0) {
        float tot = sm[0] + sm[1] + sm[2] + sm[3];
        rs[row] = 1.0f / (sqrtf(tot) * (1.0f / 64.0f) + 1e-8f);
    }
}

// ---------------------------------------------------------------------------
// i8 GEMM (R18 body): 256x128, BK=64, 3x24KB LDS, counted vmcnt(3).
// XMAP=1: L1 XCD-stripe mapping (8 m-tiles per XCD, m-major inner);
// XMAP=0: R18's original swizzle (L2 GEMM).
// ---------------------------------------------------------------------------
template <int EPI, int KDIM, int NBLKN, int XMAP>
__global__ __launch_bounds__(512) void gemm_i8t(const char* __restrict__ A,
                                                const char* __restrict__ B,
                                                char* __restrict__ Cq,
                                                float* __restrict__ Cf,
                                                const float* __restrict__ rowscale,
                                                int nwg) {
    constexpr int BUFB = 24576;
    constexpr int NT = KDIM / 64;
    __shared__ char smem[3 * BUFB];

    const int tid = threadIdx.x;
    const int bid = blockIdx.x;
    uint m0, n0;
    if (XMAP == 1) {
        // XCD x owns m-tiles [x*8, x*8+8); inner order m-major (A stripe
        // L2-resident, B panels stream once per XCD).
        const int xcd  = bid & 7;
        const int idx  = bid >> 3;              // 0..(nwg/8-1)
        const int mloc = idx & 7;
        const int n    = idx >> 3;
        m0 = (uint)(xcd * 8 + mloc) * 256u;
        n0 = (uint)n * 128u;
    } else {
        const int swz = (bid & 7) * (nwg >> 3) + (bid >> 3);
        m0 = (uint)(swz / NBLKN) * 256u;
        n0 = (uint)(swz % NBLKN) * 128u;
    }

    const int lane = tid & 63;
    const int wid  = tid >> 6;
    const int wm   = wid >> 1;                  // 0..3 -> 64-row slice
    const int wn   = wid & 1;                   // 0..1 -> 64-col slice
    const int lr   = lane & 15;
    const int lk   = lane >> 4;                 // 16B k-chunk 0..3

    // staging source (inverse swizzle)
    uint aOff[2], bOff;
    #pragma unroll
    for (int inst = 0; inst < 2; ++inst) {
        uint s = (uint)tid + (uint)inst * 512u;
        uint row = s >> 2, ch = s & 3u;
        uint src = ((ch ^ ((row >> 1) & 3u)) << 4);
        aOff[inst] = (m0 + row) * (uint)KDIM + src;
    }
    {
        uint row = (uint)tid >> 2, ch = (uint)tid & 3u;
        uint src = ((ch ^ ((row >> 1) & 3u)) << 4);
        bOff = (n0 + row) * (uint)KDIM + src;
    }
    const uint dstOff = (uint)tid * 16u;

    // fragment read offsets (bytes)
    uint offA[4], offB[4];
    #pragma unroll
    for (int i = 0; i < 4; ++i) {
        uint rowa = (uint)(wm * 64 + i * 16 + lr);
        offA[i] = rowa * 64u + (((uint)lk ^ ((rowa >> 1) & 3u)) << 4);
        uint rowb = (uint)(wn * 64 + i * 16 + lr);
        offB[i] = 16384u + rowb * 64u + (((uint)lk ^ ((rowb >> 1) & 3u)) << 4);
    }

    i32x4 acc[4][4];
    #pragma unroll
    for (int mi = 0; mi < 4; ++mi)
        #pragma unroll
        for (int ni = 0; ni < 4; ++ni)
            acc[mi][ni] = (i32x4){0, 0, 0, 0};

    // prologue: stage tiles 0 and 1
    #pragma unroll
    for (int tt = 0; tt < 2; ++tt) {
        char* sb = smem + tt * BUFB;
        const uint k0 = (uint)tt * 64u;
        gload_lds16(A + aOff[0] + k0, sb +     0 + dstOff);
        gload_lds16(A + aOff[1] + k0, sb +  8192 + dstOff);
        gload_lds16(B + bOff    + k0, sb + 16384 + dstOff);
    }
    VMCNT(3);            // tile 0 landed; tile 1's 3 in flight
    BAR();

    int cur = 0, stg = 2;
    #pragma unroll 1
    for (int t = 0; t < NT; ++t) {
        const char* cb = smem + cur * BUFB;
        char* sb = smem + stg * BUFB;
        const uint kc = (uint)(t + 2) * 64u;
        const bool doS = (t + 2 < NT);
        i32x4 av[4], bv[4];

        #pragma unroll
        for (int i = 0; i < 4; ++i) av[i] = *(const i32x4*)(cb + offA[i]);
        #pragma unroll
        for (int i = 0; i < 4; ++i) bv[i] = *(const i32x4*)(cb + offB[i]);
        if (doS) {
            gload_lds16(A + aOff[0] + kc, sb +     0 + dstOff);
            gload_lds16(A + aOff[1] + kc, sb +  8192 + dstOff);
            gload_lds16(B + bOff    + kc, sb + 16384 + dstOff);
        }
        __builtin_amdgcn_s_setprio(1);
        #pragma unroll
        for (int mi = 0; mi < 4; ++mi)
            #pragma unroll
            for (int ni = 0; ni < 4; ++ni)
                acc[mi][ni] = __builtin_amdgcn_mfma_i32_16x16x64_i8(
                    av[mi], bv[ni], acc[mi][ni], 0, 0, 0);
        __builtin_amdgcn_s_setprio(0);

        if (doS) { VMCNT(3); } else { VMCNT(0); }  // tile t+1 fully landed
        BAR();
        cur = (cur == 2) ? 0 : cur + 1;
        stg = (stg == 2) ? 0 : stg + 1;
    }

    // epilogue: C/D frag mapping col = lane&15, row = (lane>>4)*4 + reg
    constexpr uint N = (uint)NBLKN * 128u;
    #pragma unroll
    for (int mi = 0; mi < 4; ++mi) {
        #pragma unroll
        for (int j = 0; j < 4; ++j) {
            const uint gr = m0 + (uint)(wm * 64 + mi * 16 + lk * 4 + j);
            float s = 0.f;
            if (EPI == 1) s = rowscale[gr];
            #pragma unroll
            for (int ni = 0; ni < 4; ++ni) {
                const uint gc = n0 + (uint)(wn * 64 + ni * 16 + lr);
                if (EPI == 0) {
                    float g = gelu_fast((float)acc[mi][ni][j] * (1.0f / 24.0f));
                    Cq[gr * N + gc] = (char)q8(g);
                } else {
                    Cf[gr * N + gc] = (float)acc[mi][ni][j] * s;
                }
            }
        }
    }
}

// ---------------------------------------------------------------------------
extern "C" void kernel_launch(void* const* d_in, const int* in_sizes, int n_in,
                              void* d_out, int out_size, void* d_ws, size_t ws_size,
                              hipStream_t stream) {
    const float* x    = (const float*)d_in[0];
    const float* w_up = (const float*)d_in[1];
    const float* w_dn = (const float*)d_in[2];
    float* out = (float*)d_out;

    uint8_t* ws = (uint8_t*)d_ws;
    char* hq  = (char*)(ws);                                   // 64 MB
    char* xq  = (char*)(ws + 67108864);                        // 16 MB
    char* wqu = (char*)(ws + 67108864 + 16777216);             // 4 MB
    char* wqd = (char*)(ws + 67108864 + 16777216 + 4194304);   // 4 MB
    float*  rs   = (float*)(ws + 67108864 + 16777216 + 2 * 4194304);
    double* alph = (double*)(ws + 67108864 + 16777216 + 2 * 4194304 + 65536);

    hipMemsetAsync(alph, 0, 16, stream);

    absmean_reduce<<<256, 256, 0, stream>>>(w_up, alph + 0);
    absmean_reduce<<<256, 256, 0, stream>>>(w_dn, alph + 1);
    quant_w8<<<NW / 1024, 256, 0, stream>>>(w_up, alph + 0, wqu);
    quant_w8<<<NW / 1024, 256, 0, stream>>>(w_dn, alph + 1, wqd);
    rmsnorm_xq<<<M_ROWS, 256, 0, stream>>>(x, xq);

    // L1: hq = q8(gelu((xq @ wqu^T)/24))  [16384 x 4096], K=1024
    // grid 64 x 32 = 2048 blocks; XCD-stripe mapping (XMAP=1)
    gemm_i8t<0, D_MODEL, 32, 1><<<2048, 512, 0, stream>>>(
        xq, wqu, hq, nullptr, nullptr, 2048);

    rowscale_hq<<<M_ROWS, 256, 0, stream>>>(hq, rs);

    // L2: out = (hq @ wqd^T) * rs[m]  [16384 x 1024], K=4096
    // grid 64 x 8 = 512 blocks; R18 mapping (XMAP=0)
    gemm_i8t<1, D_FF, 8, 0><<<512, 512, 0, stream>>>(
        hq, wqd, nullptr, out, rs, 512);
}